// Round 16
// baseline (38.838 us; speedup 1.0000x reference)
//
#include <hip/hip_runtime.h>

#define HH  64
#define WW  96
#define CC  128
#define BB  2
#define HWI (HH*WW)

#define PXB  8           // pixels per block (x)
#define TCOL 28          // staged cols [s_tile, s_tile+28) ⊇ needed [X-9, X+17]
#define ROWB (TCOL*64)   // 1792 B per staged row
#define BUFB (20*ROWB)   // 35840 B = 35 x 1KB chunks exactly
#define NCHK 35          // DMA chunks / n-tiles per round
#define AOFF BUFB        // A tile after the single B buffer
#define ASTR 272         // A row stride
#define LDSZ (AOFF + 16*ASTR)   // 40192 B -> 4 blocks/CU capacity

typedef __attribute__((ext_vector_type(8))) _Float16 half8;
typedef __attribute__((ext_vector_type(4))) _Float16 half4;
typedef __attribute__((ext_vector_type(4))) float    f32x4;
typedef unsigned int u32;

__device__ __forceinline__ void gll16(const void* g, void* l) {
    __builtin_amdgcn_global_load_lds(
        (const __attribute__((address_space(1))) u32*)g,
        (__attribute__((address_space(3))) u32*)l, 16, 0, 0);   // width 16: HW-verified
}

// ---- prologue (verbatim R15): vectorized reads, full-line XCD-aligned writes ----
__global__ __launch_bounds__(256) void conv_i2(const float* __restrict__ I2,
                                               unsigned char* __restrict__ I2t)
{
    const int bid  = blockIdx.x;        // 0..191
    const int tid  = threadIdx.x;       // 0..255
    const int xcd  = bid & 7;
    const int s    = bid >> 3;          // 0..23
    const int b    = xcd >> 2;
    const int band = xcd & 3;
    const int kc   = s / 6;             // 0..3
    const int cs   = s - kc*6;          // 0..5
    const int g    = tid & 3;           // granule (8 ch)
    const int cq   = cs*4 + ((tid >> 2) & 3);   // col-quad 0..23
    const int row  = band*16 + (tid >> 4);
    const int col0 = cq*4;

    const float* src = I2 + ((size_t)(b*CC + kc*32 + g*8)*HH + row)*WW + col0;
    float va[8][4];
#pragma unroll
    for (int j = 0; j < 8; ++j) {
        const float4 v = *(const float4*)(src + (size_t)j*HWI);
        va[j][0] = v.x; va[j][1] = v.y; va[j][2] = v.z; va[j][3] = v.w;
    }

    unsigned char* dst = I2t + (size_t)(((b*4 + kc)*HH + row)*WW + col0)*64;
    const int sbase = g ^ (cq & 3);
#pragma unroll
    for (int k = 0; k < 4; ++k) {
        half8 h;
#pragma unroll
        for (int j = 0; j < 8; ++j) h[j] = (_Float16)va[j][k];
        *(half8*)(dst + k*64 + ((sbase ^ k) << 4)) = h;
    }
}

// ---- main (verbatim R13/R15: DMA staging + XCD swizzle; best = 20.0us) ----
__global__ __launch_bounds__(256, 4) void corr_kernel(
    const float* __restrict__ I1,
    const unsigned char* __restrict__ I2t,
    const float* __restrict__ flow,
    float* __restrict__ out)
{
    __shared__ __align__(16) unsigned char smem[LDSZ];

    const int tid  = threadIdx.x;
    const int lane = tid & 63;
    const int w    = tid >> 6;      // 4 waves

    // ---- XCD swizzle (bijective on 0..767) ----
    const int bid = blockIdx.x;
    const int xcd = bid & 7;
    const int j   = bid >> 3;       // 0..95
    const int b   = xcd >> 2;
    const int y0  = 16*(xcd & 3) + 2*(j & 7);
    const int X   = (j >> 3) * PXB;

    const int s_tile = min(max(X - 9, 0), WW - TCOL);

    const int fpx = lane & 15;
    const int kg  = lane >> 4;

    const int cpx = tid & 7;
    const int oq  = tid >> 3;
    const int xx  = X + cpx;
    float cxv[2], cyv[2];
#pragma unroll
    for (int yloc = 0; yloc < 2; ++yloc) {
        const int yy = y0 + yloc;
        cxv[yloc] = (float)xx + flow[((size_t)(b*2+0)*HH + yy)*WW + xx];
        cyv[yloc] = (float)yy + flow[((size_t)(b*2+1)*HH + yy)*WW + xx];
    }

#pragma unroll
    for (int i = 0; i < 2; ++i) {
        const int e   = tid + 256*i;
        const int q   = e & 1;
        const int ch  = (e >> 1) & 127;
        const int myy = e >> 8;
        const float4 v = *(const float4*)&I1[((size_t)(b*CC + ch)*HH + y0 + myy)*WW + X + q*4];
        const float ve[4] = { v.x, v.y, v.z, v.w };
#pragma unroll
        for (int k = 0; k < 4; ++k) {
            const int m = myy*8 + q*4 + k;
            *(_Float16*)(smem + AOFF + m*ASTR + ch*2) = (_Float16)ve[k];
        }
    }

    int boff[9];
#pragma unroll
    for (int i = 0; i < 9; ++i) {
        const int t   = min(w + 4*i, NCHK - 1);
        const int n   = t*16 + fpx;
        const int r_t = n / TCOL;
        const int c_t = n - r_t*TCOL;
        const int col = s_tile + c_t;
        boff[i] = r_t*ROWB + c_t*64 + ((kg ^ ((col ^ (col >> 2)) & 3)) << 4);
    }
    const int aoff = AOFF + fpx*ASTR + (kg << 4);

    auto stage = [&](int rr) {
#pragma unroll
        for (int i = 0; i < 9; ++i) {
            const int p = w + 4*i;
            if (p < NCHK) {
                const int z   = p*1024 + lane*16;
                const int r_t = z / ROWB;
                const int off = z - r_t*ROWB;
                const int c   = off >> 6;
                const int lb  = off & 63;
                const int grow = min(max(y0 - 9 + r_t, 0), HH - 1);
                const unsigned char* src = I2t
                    + ((size_t)(((b*4 + rr)*HH + grow)*WW + s_tile + c))*64 + lb;
                gll16(src, smem + p*1024);
            }
        }
    };

    f32x4 acc[9];
#pragma unroll
    for (int i = 0; i < 9; ++i) acc[i] = (f32x4){0.f,0.f,0.f,0.f};

    stage(0);
    __syncthreads();

#pragma unroll
    for (int r = 0; r < 4; ++r) {
        const half8 af = *(const half8*)(smem + aoff + r*64);
#pragma unroll
        for (int i = 0; i < 9; ++i) {
            if (w + 4*i < NCHK) {
                const half8 bf = *(const half8*)(smem + boff[i]);
                acc[i] = __builtin_amdgcn_mfma_f32_16x16x32_f16(af, bf, acc[i], 0, 0, 0);
            }
        }
        __syncthreads();
        if (r < 3) {
            stage(r + 1);
            __syncthreads();
        }
    }

    _Float16* D = (_Float16*)smem;
#pragma unroll
    for (int i = 0; i < 9; ++i) {
        if (w + 4*i < NCHK) {
            const int n   = (w + 4*i)*16 + fpx;
            const int r_t = n / TCOL;
            const int c_t = n - r_t*TCOL;
            const half4 hv = { (_Float16)acc[i][0], (_Float16)acc[i][1],
                               (_Float16)acc[i][2], (_Float16)acc[i][3] };
            *(half4*)(D + (c_t*21 + r_t)*20 + kg*4) = hv;
        }
    }
    __syncthreads();

#pragma unroll
    for (int yloc = 0; yloc < 2; ++yloc) {
        const int yy = y0 + yloc;
        const int m  = yloc*8 + cpx;
        const float cx = cxv[yloc], cy = cyv[yloc];
        const int x0c = (int)floorf(cx);
        const int y0c = (int)floorf(cy);
        const float wx1 = cx - (float)x0c, wx0 = 1.f - wx1;
        const float wy1 = cy - (float)y0c, wy0 = 1.f - wy1;
        float* outb = out + (size_t)b*81*HWI + (size_t)yy*WW + xx;

#pragma unroll
        for (int k = 0; k < 3; ++k) {
            const int o = oq + 32*k;
            if (o < 81) {
                const int dyi = o / 9;
                const int dxi = o - dyi*9;
                const int ix0 = x0c - 4 + dxi;
                const int iy0 = y0c - 4 + dyi;
                const bool vx0 = (ix0   >= 0) && (ix0   < WW);
                const bool vx1 = (ix0+1 >= 0) && (ix0+1 < WW);
                const bool vy0 = (iy0   >= 0) && (iy0   < HH);
                const bool vy1 = (iy0+1 >= 0) && (iy0+1 < HH);
                const int rt  = iy0 - y0 + 9;
                const int r0c = min(max(rt,     0), 19);
                const int r1c = min(max(rt + 1, 0), 19);
                const int c0  = ix0 - s_tile;
                const int c0c = min(max(c0,     0), TCOL-1);
                const int c1c = min(max(c0 + 1, 0), TCOL-1);
                const float d00 = (float)D[(c0c*21 + r0c)*20 + m];
                const float d01 = (float)D[(c1c*21 + r0c)*20 + m];
                const float d10 = (float)D[(c0c*21 + r1c)*20 + m];
                const float d11 = (float)D[(c1c*21 + r1c)*20 + m];
                const float r0 = (vx0 ? wx0*d00 : 0.f) + (vx1 ? wx1*d01 : 0.f);
                const float r1 = (vx0 ? wx0*d10 : 0.f) + (vx1 ? wx1*d11 : 0.f);
                const float v  = (vy0 ? wy0*r0 : 0.f) + (vy1 ? wy1*r1 : 0.f);
                outb[(size_t)o*HWI] = v;
            }
        }
    }
}

extern "C" void kernel_launch(void* const* d_in, const int* in_sizes, int n_in,
                              void* d_out, int out_size, void* d_ws, size_t ws_size,
                              hipStream_t stream)
{
    const float* I1   = (const float*)d_in[0];
    const float* I2   = (const float*)d_in[1];
    const float* flow = (const float*)d_in[2];
    float* out = (float*)d_out;
    unsigned char* I2t = (unsigned char*)d_ws;   // 3,145,728 B

    // ---- ATTRIBUTION PROBE: conv launched 8x (idempotent, rewrites identical
    // I2t), then corr once. dur - 20.1 = 7 * (conv + node_overhead).
    // Kernels byte-identical to R15 -- measurement round.
#pragma unroll
    for (int rep = 0; rep < 8; ++rep) {
        conv_i2<<<dim3(192), dim3(256), 0, stream>>>(I2, I2t);
    }
    corr_kernel<<<dim3(768), dim3(256), 0, stream>>>(I1, I2t, flow, out);
}

// Round 17
// 20.511 us; speedup vs baseline: 1.8935x; 1.8935x over previous
//
#include <hip/hip_runtime.h>

#define HH  64
#define WW  96
#define CC  128
#define BB  2
#define HWI (HH*WW)

#define PXB  8           // pixels per block (x)
#define TCOL 28          // staged cols [s_tile, s_tile+28) ⊇ needed [X-9, X+17]
#define ROWB (TCOL*64)   // 1792 B per staged row
#define BUFB (20*ROWB)   // 35840 B = 35 x 1KB chunks exactly
#define NCHK 35          // DMA chunks / n-tiles per round
#define AOFF BUFB        // A tile after the single B buffer
#define ASTR 272         // A row stride
#define LDSZ (AOFF + 16*ASTR)   // 40192 B -> 4 blocks/CU capacity
#define SROWS 35         // private slice rows per XCD band: clamp(16*band-9 .. +25)
#define SLICE (SROWS*WW) // 3360 lines of 64B per (xcd,kc)

typedef __attribute__((ext_vector_type(8))) _Float16 half8;
typedef __attribute__((ext_vector_type(4))) _Float16 half4;
typedef __attribute__((ext_vector_type(4))) float    f32x4;
typedef unsigned int u32;

__device__ __forceinline__ void gll16(const void* g, void* l) {
    __builtin_amdgcn_global_load_lds(
        (const __attribute__((address_space(1))) u32*)g,
        (__attribute__((address_space(3))) u32*)l, 16, 0, 0);   // width 16: HW-verified
}

// ---- prologue: I2 fp32 -> PER-XCD private fp16 slices
//      I2t[xcd][kc][srow 0..34][col][4 slots x 16B], row-clamp baked:
//      slice row srow holds image row clamp(16*band - 9 + srow, 0, 63).
//      Block bid&7 = producing & consuming XCD -> slices are created AND
//      consumed in the same L2: no cross-XCD dirty-line probes in corr. ----
__global__ __launch_bounds__(256) void conv_i2(const float* __restrict__ I2,
                                               unsigned char* __restrict__ I2t)
{
    const int bid = blockIdx.x;            // 0..1679 (210 per xcd)
    const int tid = threadIdx.x;
    const int xcd = bid & 7;
    const int u   = (bid >> 3)*256 + tid;  // 0..53759 = 4kc * 35srow * 96col * 4g
    const int g   = u & 3;                 // granule (8 ch)
    const int v   = u >> 2;                // 0..13439
    const int col = v % WW;
    const int t2  = v / WW;                // 0..139
    const int srow = t2 % SROWS;
    const int kc   = t2 / SROWS;           // 0..3
    const int b    = xcd >> 2;
    const int band = xcd & 3;
    const int grow = min(max(16*band - 9 + srow, 0), HH - 1);

    const float* src = I2 + ((size_t)(b*CC + kc*32 + g*8)*HH + grow)*WW + col;
    half8 h;
#pragma unroll
    for (int j = 0; j < 8; ++j) h[j] = (_Float16)src[(size_t)j*HWI];

    const int slot = g ^ ((col ^ (col >> 2)) & 3);   // same XOR as R13-R15
    *(half8*)(I2t + ((size_t)((xcd*4 + kc)*SLICE + srow*WW + col))*64 + slot*16) = h;
}

// ---- main (R13/R15 body; staging now reads this XCD's private slice,
//      linear rows, no clamp -- all local-L2 hits) ----
__global__ __launch_bounds__(256, 4) void corr_kernel(
    const float* __restrict__ I1,
    const unsigned char* __restrict__ I2t,
    const float* __restrict__ flow,
    float* __restrict__ out)
{
    __shared__ __align__(16) unsigned char smem[LDSZ];

    const int tid  = threadIdx.x;
    const int lane = tid & 63;
    const int w    = tid >> 6;      // 4 waves

    // ---- XCD swizzle (bijective on 0..767) ----
    const int bid = blockIdx.x;
    const int xcd = bid & 7;
    const int j   = bid >> 3;       // 0..95
    const int b   = xcd >> 2;
    const int y0  = 16*(xcd & 3) + 2*(j & 7);
    const int X   = (j >> 3) * PXB;

    const int s_tile = min(max(X - 9, 0), WW - TCOL);
    const int srow0  = 2*(j & 7);   // staged rows = slice rows [srow0, srow0+20)

    const int fpx = lane & 15;
    const int kg  = lane >> 4;

    // ---- hoisted combine identity + flow loads ----
    const int cpx = tid & 7;
    const int oq  = tid >> 3;
    const int xx  = X + cpx;
    float cxv[2], cyv[2];
#pragma unroll
    for (int yloc = 0; yloc < 2; ++yloc) {
        const int yy = y0 + yloc;
        cxv[yloc] = (float)xx + flow[((size_t)(b*2+0)*HH + yy)*WW + xx];
        cyv[yloc] = (float)yy + flow[((size_t)(b*2+1)*HH + yy)*WW + xx];
    }

    // ---- stage A: fp16 [m16][ch128] stride 272B, float4 I1 loads ----
#pragma unroll
    for (int i = 0; i < 2; ++i) {
        const int e   = tid + 256*i;
        const int q   = e & 1;
        const int ch  = (e >> 1) & 127;
        const int myy = e >> 8;
        const float4 v = *(const float4*)&I1[((size_t)(b*CC + ch)*HH + y0 + myy)*WW + X + q*4];
        const float ve[4] = { v.x, v.y, v.z, v.w };
#pragma unroll
        for (int k = 0; k < 4; ++k) {
            const int m = myy*8 + q*4 + k;
            *(_Float16*)(smem + AOFF + m*ASTR + ch*2) = (_Float16)ve[k];
        }
    }

    // ---- hoisted B-fragment offsets (XOR keyed on global col; unchanged) ----
    int boff[9];
#pragma unroll
    for (int i = 0; i < 9; ++i) {
        const int t   = min(w + 4*i, NCHK - 1);
        const int n   = t*16 + fpx;
        const int r_t = n / TCOL;
        const int c_t = n - r_t*TCOL;
        const int col = s_tile + c_t;
        boff[i] = r_t*ROWB + c_t*64 + ((kg ^ ((col ^ (col >> 2)) & 3)) << 4);
    }
    const int aoff = AOFF + fpx*ASTR + (kg << 4);

    // ---- async staging from this XCD's private slice (linear, no clamp) ----
    const unsigned char* sbase = I2t + (size_t)(xcd*4)*SLICE*64;
    auto stage = [&](int rr) {
#pragma unroll
        for (int i = 0; i < 9; ++i) {
            const int p = w + 4*i;              // wave-uniform
            if (p < NCHK) {
                const int z   = p*1024 + lane*16;
                const int r_t = z / ROWB;           // staged row 0..19
                const int off = z - r_t*ROWB;
                const int c   = off >> 6;
                const int lb  = off & 63;
                const unsigned char* src = sbase
                    + ((size_t)(rr*SLICE + (srow0 + r_t)*WW + s_tile + c))*64 + lb;
                gll16(src, smem + p*1024);
            }
        }
    };

    f32x4 acc[9];
#pragma unroll
    for (int i = 0; i < 9; ++i) acc[i] = (f32x4){0.f,0.f,0.f,0.f};

    stage(0);
    __syncthreads();                 // A visible + DMA(0) drained

#pragma unroll
    for (int r = 0; r < 4; ++r) {
        const half8 af = *(const half8*)(smem + aoff + r*64);
#pragma unroll
        for (int i = 0; i < 9; ++i) {
            if (w + 4*i < NCHK) {
                const half8 bf = *(const half8*)(smem + boff[i]);
                acc[i] = __builtin_amdgcn_mfma_f32_16x16x32_f16(af, bf, acc[i], 0, 0, 0);
            }
        }
        __syncthreads();
        if (r < 3) {
            stage(r + 1);
            __syncthreads();
        }
    }

    // ---- dump D fp16 [c28][r pad21][m pad20] via ds_write_b64 ----
    _Float16* D = (_Float16*)smem;
#pragma unroll
    for (int i = 0; i < 9; ++i) {
        if (w + 4*i < NCHK) {
            const int n   = (w + 4*i)*16 + fpx;
            const int r_t = n / TCOL;
            const int c_t = n - r_t*TCOL;
            const half4 hv = { (_Float16)acc[i][0], (_Float16)acc[i][1],
                               (_Float16)acc[i][2], (_Float16)acc[i][3] };
            *(half4*)(D + (c_t*21 + r_t)*20 + kg*4) = hv;
        }
    }
    __syncthreads();

    // ---- combine: 81 outputs x (8px, 2rows), shared bilinear weights ----
#pragma unroll
    for (int yloc = 0; yloc < 2; ++yloc) {
        const int yy = y0 + yloc;
        const int m  = yloc*8 + cpx;
        const float cx = cxv[yloc], cy = cyv[yloc];
        const int x0c = (int)floorf(cx);
        const int y0c = (int)floorf(cy);
        const float wx1 = cx - (float)x0c, wx0 = 1.f - wx1;
        const float wy1 = cy - (float)y0c, wy0 = 1.f - wy1;
        float* outb = out + (size_t)b*81*HWI + (size_t)yy*WW + xx;

#pragma unroll
        for (int k = 0; k < 3; ++k) {
            const int o = oq + 32*k;
            if (o < 81) {
                const int dyi = o / 9;
                const int dxi = o - dyi*9;
                const int ix0 = x0c - 4 + dxi;
                const int iy0 = y0c - 4 + dyi;
                const bool vx0 = (ix0   >= 0) && (ix0   < WW);
                const bool vx1 = (ix0+1 >= 0) && (ix0+1 < WW);
                const bool vy0 = (iy0   >= 0) && (iy0   < HH);
                const bool vy1 = (iy0+1 >= 0) && (iy0+1 < HH);
                const int rt  = iy0 - y0 + 9;
                const int r0c = min(max(rt,     0), 19);
                const int r1c = min(max(rt + 1, 0), 19);
                const int c0  = ix0 - s_tile;
                const int c0c = min(max(c0,     0), TCOL-1);
                const int c1c = min(max(c0 + 1, 0), TCOL-1);
                const float d00 = (float)D[(c0c*21 + r0c)*20 + m];
                const float d01 = (float)D[(c1c*21 + r0c)*20 + m];
                const float d10 = (float)D[(c0c*21 + r1c)*20 + m];
                const float d11 = (float)D[(c1c*21 + r1c)*20 + m];
                const float r0 = (vx0 ? wx0*d00 : 0.f) + (vx1 ? wx1*d01 : 0.f);
                const float r1 = (vx0 ? wx0*d10 : 0.f) + (vx1 ? wx1*d11 : 0.f);
                const float v  = (vy0 ? wy0*r0 : 0.f) + (vy1 ? wy1*r1 : 0.f);
                outb[(size_t)o*HWI] = v;
            }
        }
    }
}

extern "C" void kernel_launch(void* const* d_in, const int* in_sizes, int n_in,
                              void* d_out, int out_size, void* d_ws, size_t ws_size,
                              hipStream_t stream)
{
    const float* I1   = (const float*)d_in[0];
    const float* I2   = (const float*)d_in[1];
    const float* flow = (const float*)d_in[2];
    float* out = (float*)d_out;
    unsigned char* I2t = (unsigned char*)d_ws;   // 6,881,280 B private slices

    conv_i2<<<dim3(1680), dim3(256), 0, stream>>>(I2, I2t);
    corr_kernel<<<dim3(768), dim3(256), 0, stream>>>(I1, I2t, flow, out);
}